// Round 1
// baseline (804.878 us; speedup 1.0000x reference)
//
#include <hip/hip_runtime.h>

// PhysicsLoss: fused base-MSE + boundary MSE + continuity + NS-residual losses.
// inputs  (256,1,128,128) f32, outputs (256,3,128,128) f32, targets (256,3,128,128) f32
// -> scalar f32.

#define HH 128
#define WW 128
#define BB 256
#define NI 126  // interior size (1:H-1)

__global__ void zero_ws_kernel(double* ws) {
    if (threadIdx.x < 4) ws[threadIdx.x] = 0.0;
}

// torch.gradient semantics on an array of length NI:
// one-sided 1st-order at edges, central 2nd-order interior.
template <class G>
__device__ __forceinline__ float grad1(const G& g, int i, float inv_h, float inv_2h) {
    if (i == 0) return (g(1) - g(0)) * inv_h;
    if (i == NI - 1) return (g(NI - 1) - g(NI - 2)) * inv_h;
    return (g(i + 1) - g(i - 1)) * inv_2h;
}

template <class G>
__device__ __forceinline__ float grad2(const G& g, int i, float inv_h, float inv_2h) {
    auto d = [&](int j) { return grad1(g, j, inv_h, inv_2h); };
    return grad1(d, i, inv_h, inv_2h);
}

__global__ __launch_bounds__(256) void physics_loss_kernel(
    const float* __restrict__ inp, const float* __restrict__ out,
    const float* __restrict__ tgt, double* __restrict__ ws) {
    const int tid = threadIdx.x;
    const int c = tid & (WW - 1);
    const int r = ((blockIdx.x & 63) << 1) | (tid >> 7);  // 2 rows per block
    const int b = blockIdx.x >> 6;

    const float* O = out + (size_t)b * 3 * HH * WW;
    const float* T = tgt + (size_t)b * 3 * HH * WW;
    const float* A = inp + (size_t)b * HH * WW;
    const int pix = r * WW + c;

    const float p = O[pix];
    const float u = O[HH * WW + pix];
    const float v = O[2 * HH * WW + pix];

    float s_base, s_bc = 0.f, s_cont = 0.f, s_ns = 0.f;
    {
        float d0 = p - T[pix];
        float d1 = u - T[HH * WW + pix];
        float d2 = v - T[2 * HH * WW + pix];
        s_base = d0 * d0 + d1 * d1 + d2 * d2;
    }

    // ---- boundary pieces (with corner multiplicity, matching the concat) ----
    const bool midrow = (r >= 55 && r < 73);  // IN_BOT=55, IN_TOP=73
    if (c == 0 && midrow) { float d = u - 0.01f; s_bc += d * d; }
    if (c == WW - 1 && midrow) { s_bc += p * p; }
    if (r == 0 || r == HH - 1) { s_bc += u * u + v * v; }          // full rows, u & v
    if ((c == 0 || c == WW - 1) && !midrow) { s_bc += u * u + v * v; }  // cols minus mid gap

    // ---- interior: continuity + NS residual ----
    if (r >= 1 && r <= HH - 2 && c >= 1 && c <= WW - 2) {
        const int ir = r - 1, ic = c - 1;
        const float* P = O;
        const float* U = O + HH * WW;
        const float* V = O + 2 * HH * WW;
        const float inv_sx = 127.0f / 1.2f, inv_2sx = 127.0f / 2.4f;
        const float inv_sy = 127.0f / 0.8f, inv_2sy = 127.0f / 1.6f;

        auto Ux = [&](int j) { return U[(ir + 1) * WW + (j + 1)]; };
        auto Uy = [&](int j) { return U[(j + 1) * WW + (ic + 1)]; };
        auto Vx = [&](int j) { return V[(ir + 1) * WW + (j + 1)]; };
        auto Vy = [&](int j) { return V[(j + 1) * WW + (ic + 1)]; };
        auto Px = [&](int j) { return P[(ir + 1) * WW + (j + 1)]; };
        auto Py = [&](int j) { return P[(j + 1) * WW + (ic + 1)]; };

        const float du_dx = grad1(Ux, ic, inv_sx, inv_2sx);
        const float du_dy = grad1(Uy, ir, inv_sy, inv_2sy);
        const float dv_dx = grad1(Vx, ic, inv_sx, inv_2sx);
        const float dv_dy = grad1(Vy, ir, inv_sy, inv_2sy);
        const float dp_dx = grad1(Px, ic, inv_sx, inv_2sx);
        const float dp_dy = grad1(Py, ir, inv_sy, inv_2sy);
        const float du_dxx = grad2(Ux, ic, inv_sx, inv_2sx);
        const float du_dyy = grad2(Uy, ir, inv_sy, inv_2sy);
        const float dv_dxx = grad2(Vx, ic, inv_sx, inv_2sx);
        const float dv_dyy = grad2(Vy, ir, inv_sy, inv_2sy);

        const float alpha = A[pix];
        const float dv = du_dx + dv_dy;
        s_cont = dv * dv;
        // RHO = MU = 1
        const float xr = u * du_dx + v * du_dy + dp_dx - (du_dxx + du_dyy) + alpha * u;
        const float yr = u * dv_dx + v * dv_dy + dp_dy - (dv_dxx + dv_dyy) + alpha * v;
        s_ns = xr * xr + yr * yr;
    }

    // ---- reduction: wave shuffle -> LDS -> per-block double atomics ----
    #pragma unroll
    for (int off = 32; off > 0; off >>= 1) {
        s_base += __shfl_down(s_base, off);
        s_bc   += __shfl_down(s_bc, off);
        s_cont += __shfl_down(s_cont, off);
        s_ns   += __shfl_down(s_ns, off);
    }
    __shared__ float red[4][4];
    const int wave = tid >> 6, lane = tid & 63;
    if (lane == 0) {
        red[wave][0] = s_base; red[wave][1] = s_bc;
        red[wave][2] = s_cont; red[wave][3] = s_ns;
    }
    __syncthreads();
    if (tid == 0) {
        double a0 = 0, a1 = 0, a2 = 0, a3 = 0;
        #pragma unroll
        for (int w = 0; w < 4; ++w) {
            a0 += red[w][0]; a1 += red[w][1]; a2 += red[w][2]; a3 += red[w][3];
        }
        atomicAdd(&ws[0], a0);
        atomicAdd(&ws[1], a1);
        atomicAdd(&ws[2], a2);
        atomicAdd(&ws[3], a3);
    }
}

__global__ void finalize_kernel(const double* __restrict__ ws, float* __restrict__ out) {
    const double loss_base = ws[0] / 300000.0;
    const double loss_cont = ws[2] / (256.0 * 126.0 * 126.0) / 1e-5;
    const double loss_ns   = ws[3] / (2.0 * 256.0 * 126.0 * 126.0) / 0.01;
    const double loss_bc   = ws[1] / (256.0 * 988.0);
    out[0] = (float)(0.10000000000000009 * loss_base +
                     0.3 * (loss_cont + loss_ns + loss_bc));
}

extern "C" void kernel_launch(void* const* d_in, const int* in_sizes, int n_in,
                              void* d_out, int out_size, void* d_ws, size_t ws_size,
                              hipStream_t stream) {
    const float* inp = (const float*)d_in[0];
    const float* out = (const float*)d_in[1];
    const float* tgt = (const float*)d_in[2];
    float* o = (float*)d_out;
    double* ws = (double*)d_ws;

    hipLaunchKernelGGL(zero_ws_kernel, dim3(1), dim3(64), 0, stream, ws);
    hipLaunchKernelGGL(physics_loss_kernel, dim3(BB * (HH / 2)), dim3(256), 0, stream,
                       inp, out, tgt, ws);
    hipLaunchKernelGGL(finalize_kernel, dim3(1), dim3(1), 0, stream, ws, o);
}

// Round 2
// 67.374 us; speedup vs baseline: 11.9463x; 11.9463x over previous
//
#include <hip/hip_runtime.h>

// PhysicsLoss: fused base-MSE + boundary MSE + continuity + NS-residual losses.
// inputs  (256,1,128,128) f32, outputs (256,3,128,128) f32, targets (256,3,128,128) f32
// -> scalar f32.
//
// R1: replace 16384-block same-address f64 atomics (12ns-serialized cacheline
// bounce, 797us) with two-stage reduction: 1024 blocks x 16 units each, private
// partial slots, then a 1-block finalize.

#define HH 128
#define WW 128
#define BB 256
#define NI 126   // interior size (1:H-1)
#define NBLK 1024
#define ITERS 16 // (256 batches * 64 row-pairs) / NBLK

__global__ void zero_ws_kernel(double* ws) {
    if (threadIdx.x < 4) ws[threadIdx.x] = 0.0;
}

// torch.gradient semantics on an array of length NI:
// one-sided 1st-order at edges, central 2nd-order interior.
template <class G>
__device__ __forceinline__ float grad1(const G& g, int i, float inv_h, float inv_2h) {
    if (i == 0) return (g(1) - g(0)) * inv_h;
    if (i == NI - 1) return (g(NI - 1) - g(NI - 2)) * inv_h;
    return (g(i + 1) - g(i - 1)) * inv_2h;
}

template <class G>
__device__ __forceinline__ float grad2(const G& g, int i, float inv_h, float inv_2h) {
    auto d = [&](int j) { return grad1(g, j, inv_h, inv_2h); };
    return grad1(d, i, inv_h, inv_2h);
}

__global__ __launch_bounds__(256) void physics_loss_kernel(
    const float* __restrict__ inp, const float* __restrict__ out,
    const float* __restrict__ tgt, double* __restrict__ ws) {
    const int tid = threadIdx.x;
    const int c = tid & (WW - 1);
    const int half = tid >> 7;

    double a_base = 0.0, a_bc = 0.0, a_cont = 0.0, a_ns = 0.0;

    for (int it = 0; it < ITERS; ++it) {
        const int unit = blockIdx.x * ITERS + it;   // consecutive units -> halo reuse
        const int r = ((unit & 63) << 1) | half;
        const int b = unit >> 6;

        const float* O = out + (size_t)b * 3 * HH * WW;
        const float* T = tgt + (size_t)b * 3 * HH * WW;
        const float* A = inp + (size_t)b * HH * WW;
        const int pix = r * WW + c;

        const float p = O[pix];
        const float u = O[HH * WW + pix];
        const float v = O[2 * HH * WW + pix];

        float s_base, s_bc = 0.f, s_cont = 0.f, s_ns = 0.f;
        {
            float d0 = p - T[pix];
            float d1 = u - T[HH * WW + pix];
            float d2 = v - T[2 * HH * WW + pix];
            s_base = d0 * d0 + d1 * d1 + d2 * d2;
        }

        // ---- boundary pieces (corner multiplicity matches the concat) ----
        const bool midrow = (r >= 55 && r < 73);  // IN_BOT=55, IN_TOP=73
        if (c == 0 && midrow) { float d = u - 0.01f; s_bc += d * d; }
        if (c == WW - 1 && midrow) { s_bc += p * p; }
        if (r == 0 || r == HH - 1) { s_bc += u * u + v * v; }
        if ((c == 0 || c == WW - 1) && !midrow) { s_bc += u * u + v * v; }

        // ---- interior: continuity + NS residual ----
        if (r >= 1 && r <= HH - 2 && c >= 1 && c <= WW - 2) {
            const int ir = r - 1, ic = c - 1;
            const float* P = O;
            const float* U = O + HH * WW;
            const float* V = O + 2 * HH * WW;
            const float inv_sx = 127.0f / 1.2f, inv_2sx = 127.0f / 2.4f;
            const float inv_sy = 127.0f / 0.8f, inv_2sy = 127.0f / 1.6f;

            auto Ux = [&](int j) { return U[(ir + 1) * WW + (j + 1)]; };
            auto Uy = [&](int j) { return U[(j + 1) * WW + (ic + 1)]; };
            auto Vx = [&](int j) { return V[(ir + 1) * WW + (j + 1)]; };
            auto Vy = [&](int j) { return V[(j + 1) * WW + (ic + 1)]; };
            auto Px = [&](int j) { return P[(ir + 1) * WW + (j + 1)]; };
            auto Py = [&](int j) { return P[(j + 1) * WW + (ic + 1)]; };

            const float du_dx = grad1(Ux, ic, inv_sx, inv_2sx);
            const float du_dy = grad1(Uy, ir, inv_sy, inv_2sy);
            const float dv_dx = grad1(Vx, ic, inv_sx, inv_2sx);
            const float dv_dy = grad1(Vy, ir, inv_sy, inv_2sy);
            const float dp_dx = grad1(Px, ic, inv_sx, inv_2sx);
            const float dp_dy = grad1(Py, ir, inv_sy, inv_2sy);
            const float du_dxx = grad2(Ux, ic, inv_sx, inv_2sx);
            const float du_dyy = grad2(Uy, ir, inv_sy, inv_2sy);
            const float dv_dxx = grad2(Vx, ic, inv_sx, inv_2sx);
            const float dv_dyy = grad2(Vy, ir, inv_sy, inv_2sy);

            const float alpha = A[pix];
            const float dv = du_dx + dv_dy;
            s_cont = dv * dv;
            // RHO = MU = 1
            const float xr = u * du_dx + v * du_dy + dp_dx - (du_dxx + du_dyy) + alpha * u;
            const float yr = u * dv_dx + v * dv_dy + dp_dy - (dv_dxx + dv_dyy) + alpha * v;
            s_ns = xr * xr + yr * yr;
        }

        a_base += s_base; a_bc += s_bc; a_cont += s_cont; a_ns += s_ns;
    }

    // ---- block reduction: wave shuffle -> LDS -> one private slot write ----
    #pragma unroll
    for (int off = 32; off > 0; off >>= 1) {
        a_base += __shfl_down(a_base, off);
        a_bc   += __shfl_down(a_bc, off);
        a_cont += __shfl_down(a_cont, off);
        a_ns   += __shfl_down(a_ns, off);
    }
    __shared__ double red[4][4];
    const int wave = tid >> 6, lane = tid & 63;
    if (lane == 0) {
        red[wave][0] = a_base; red[wave][1] = a_bc;
        red[wave][2] = a_cont; red[wave][3] = a_ns;
    }
    __syncthreads();
    if (tid == 0) {
        double b0 = 0, b1 = 0, b2 = 0, b3 = 0;
        #pragma unroll
        for (int w = 0; w < 4; ++w) {
            b0 += red[w][0]; b1 += red[w][1]; b2 += red[w][2]; b3 += red[w][3];
        }
        double* slot = ws + (size_t)blockIdx.x * 4;
        slot[0] = b0; slot[1] = b1; slot[2] = b2; slot[3] = b3;
    }
}

__global__ __launch_bounds__(256) void finalize_kernel(const double* __restrict__ ws,
                                                       float* __restrict__ out) {
    const int tid = threadIdx.x;
    double a0 = 0, a1 = 0, a2 = 0, a3 = 0;
    for (int b = tid; b < NBLK; b += 256) {
        const double* p = ws + (size_t)b * 4;
        a0 += p[0]; a1 += p[1]; a2 += p[2]; a3 += p[3];
    }
    #pragma unroll
    for (int off = 32; off > 0; off >>= 1) {
        a0 += __shfl_down(a0, off);
        a1 += __shfl_down(a1, off);
        a2 += __shfl_down(a2, off);
        a3 += __shfl_down(a3, off);
    }
    __shared__ double red[4][4];
    const int wave = tid >> 6, lane = tid & 63;
    if (lane == 0) {
        red[wave][0] = a0; red[wave][1] = a1; red[wave][2] = a2; red[wave][3] = a3;
    }
    __syncthreads();
    if (tid == 0) {
        double b0 = 0, b1 = 0, b2 = 0, b3 = 0;
        #pragma unroll
        for (int w = 0; w < 4; ++w) {
            b0 += red[w][0]; b1 += red[w][1]; b2 += red[w][2]; b3 += red[w][3];
        }
        const double loss_base = b0 / 300000.0;
        const double loss_cont = b2 / (256.0 * 126.0 * 126.0) / 1e-5;
        const double loss_ns   = b3 / (2.0 * 256.0 * 126.0 * 126.0) / 0.01;
        const double loss_bc   = b1 / (256.0 * 988.0);
        out[0] = (float)(0.10000000000000009 * loss_base +
                         0.3 * (loss_cont + loss_ns + loss_bc));
    }
}

extern "C" void kernel_launch(void* const* d_in, const int* in_sizes, int n_in,
                              void* d_out, int out_size, void* d_ws, size_t ws_size,
                              hipStream_t stream) {
    const float* inp = (const float*)d_in[0];
    const float* out = (const float*)d_in[1];
    const float* tgt = (const float*)d_in[2];
    float* o = (float*)d_out;
    double* ws = (double*)d_ws;

    hipLaunchKernelGGL(physics_loss_kernel, dim3(NBLK), dim3(256), 0, stream,
                       inp, out, tgt, ws);
    hipLaunchKernelGGL(finalize_kernel, dim3(1), dim3(256), 0, stream, ws, o);
}

// Round 3
// 55.036 us; speedup vs baseline: 14.6245x; 1.2242x over previous
//
#include <hip/hip_runtime.h>

// PhysicsLoss: fused base-MSE + boundary MSE + continuity + NS-residual losses.
// inputs  (256,1,128,128) f32, outputs (256,3,128,128) f32, targets (256,3,128,128) f32
// -> scalar f32.
//
// R2: float4 register tiling. Each thread computes 4 consecutive pixels from 23
// independent float4 loads (vs ~30 scalar loads/pixel before). All stencil
// indices are compile-time constant (relative indexing, unrolled q) so the
// register arrays stay in VGPRs. 4096 blocks x 256 threads, single shot.

#define HH 128
#define WW 128
#define NI 126   // interior size (1:H-1)
#define NBLK 4096

// torch.gradient semantics, relative accessor form: g(d) = value at interior
// index (ic+d). All call sites pass literal d -> constant register indices.
template <class G>
__device__ __forceinline__ float g1f(const G& g, int ic, float inv_h, float inv_2h) {
    if (ic == 0) return (g(1) - g(0)) * inv_h;
    if (ic == NI - 1) return (g(0) - g(-1)) * inv_h;
    return (g(1) - g(-1)) * inv_2h;
}

template <class G>
__device__ __forceinline__ float g2f(const G& g, int ic, float inv_h, float inv_2h) {
    auto d = [&](int dd) {
        const int j = ic + dd;
        if (j == 0) return (g(dd + 1) - g(dd)) * inv_h;
        if (j == NI - 1) return (g(dd) - g(dd - 1)) * inv_h;
        return (g(dd + 1) - g(dd - 1)) * inv_2h;
    };
    if (ic == 0) return (d(1) - d(0)) * inv_h;
    if (ic == NI - 1) return (d(0) - d(-1)) * inv_h;
    return (d(1) - d(-1)) * inv_2h;
}

__global__ __launch_bounds__(256) void physics_loss_kernel(
    const float* __restrict__ inp, const float* __restrict__ out,
    const float* __restrict__ tgt, double* __restrict__ ws) {
    const int tid = threadIdx.x;
    const int grp = tid & 31;        // float4 group within row (32 per row)
    const int rloc = tid >> 5;       // 8 rows per block
    const int bid = blockIdx.x;
    const int b = bid >> 4;          // batch
    const int r = ((bid & 15) << 3) | rloc;
    const int c0 = grp << 2;

    const float* O = out + (size_t)b * 3 * HH * WW;
    const float* T = tgt + (size_t)b * 3 * HH * WW;
    const float* A = inp + (size_t)b * HH * WW;
    const float* P = O;
    const float* U = O + HH * WW;
    const float* V = O + 2 * HH * WW;

    const int gl = grp == 0 ? 0 : grp - 1;
    const int gr = grp == 31 ? 31 : grp + 1;
    const int rm2 = r < 2 ? 0 : r - 2;
    const int rm1 = r < 1 ? 0 : r - 1;
    const int rp1 = r > 126 ? 127 : r + 1;
    const int rp2 = r > 125 ? 127 : r + 2;

    auto ld = [&](const float* base, int row, int gg) {
        return reinterpret_cast<const float4*>(base + row * WW)[gg];
    };

    // 23 independent float4 loads
    const float4 uxl = ld(U, r, gl), uxm = ld(U, r, grp), uxr = ld(U, r, gr);
    const float4 uym2 = ld(U, rm2, grp), uym1 = ld(U, rm1, grp);
    const float4 uyp1 = ld(U, rp1, grp), uyp2 = ld(U, rp2, grp);
    const float4 vxl = ld(V, r, gl), vxm = ld(V, r, grp), vxr = ld(V, r, gr);
    const float4 vym2 = ld(V, rm2, grp), vym1 = ld(V, rm1, grp);
    const float4 vyp1 = ld(V, rp1, grp), vyp2 = ld(V, rp2, grp);
    const float4 pxl = ld(P, r, gl), pxm = ld(P, r, grp), pxr = ld(P, r, gr);
    const float4 pym1 = ld(P, rm1, grp), pyp1 = ld(P, rp1, grp);
    const float4 t0 = ld(T, r, grp);
    const float4 t1 = ld(T + HH * WW, r, grp);
    const float4 t2 = ld(T + 2 * HH * WW, r, grp);
    const float4 av = ld(A, r, grp);

    const float xu[12] = {uxl.x, uxl.y, uxl.z, uxl.w, uxm.x, uxm.y, uxm.z, uxm.w,
                          uxr.x, uxr.y, uxr.z, uxr.w};
    const float xv[12] = {vxl.x, vxl.y, vxl.z, vxl.w, vxm.x, vxm.y, vxm.z, vxm.w,
                          vxr.x, vxr.y, vxr.z, vxr.w};
    const float xp[12] = {pxl.x, pxl.y, pxl.z, pxl.w, pxm.x, pxm.y, pxm.z, pxm.w,
                          pxr.x, pxr.y, pxr.z, pxr.w};
    const float yu[4][4] = {{uym2.x, uym2.y, uym2.z, uym2.w},
                            {uym1.x, uym1.y, uym1.z, uym1.w},
                            {uyp1.x, uyp1.y, uyp1.z, uyp1.w},
                            {uyp2.x, uyp2.y, uyp2.z, uyp2.w}};
    const float yv[4][4] = {{vym2.x, vym2.y, vym2.z, vym2.w},
                            {vym1.x, vym1.y, vym1.z, vym1.w},
                            {vyp1.x, vyp1.y, vyp1.z, vyp1.w},
                            {vyp2.x, vyp2.y, vyp2.z, vyp2.w}};
    const float pm1[4] = {pym1.x, pym1.y, pym1.z, pym1.w};
    const float pp1[4] = {pyp1.x, pyp1.y, pyp1.z, pyp1.w};
    const float tt0[4] = {t0.x, t0.y, t0.z, t0.w};
    const float tt1[4] = {t1.x, t1.y, t1.z, t1.w};
    const float tt2[4] = {t2.x, t2.y, t2.z, t2.w};
    const float aa[4] = {av.x, av.y, av.z, av.w};

    const float inv_sx = 127.0f / 1.2f, inv_2sx = 127.0f / 2.4f;
    const float inv_sy = 127.0f / 0.8f, inv_2sy = 127.0f / 1.6f;

    float s_base = 0.f, s_bc = 0.f, s_cont = 0.f, s_ns = 0.f;
    const bool midrow = (r >= 55 && r < 73);  // IN_BOT=55, IN_TOP=73

    #pragma unroll
    for (int q = 0; q < 4; ++q) {
        const int c = c0 + q;
        const float p = xp[4 + q], u = xu[4 + q], v = xv[4 + q];
        {
            const float d0 = p - tt0[q], d1 = u - tt1[q], d2 = v - tt2[q];
            s_base += d0 * d0 + d1 * d1 + d2 * d2;
        }
        // boundary pieces (corner multiplicity matches the reference concat)
        if (c == 0 && midrow) { const float d = u - 0.01f; s_bc += d * d; }
        if (c == WW - 1 && midrow) { s_bc += p * p; }
        if (r == 0 || r == HH - 1) { s_bc += u * u + v * v; }
        if ((c == 0 || c == WW - 1) && !midrow) { s_bc += u * u + v * v; }

        if (r >= 1 && r <= HH - 2 && c >= 1 && c <= WW - 2) {
            const int ic = c - 1, ir = r - 1;
            auto gxu = [&](int d) { return xu[q + 4 + d]; };
            auto gxv = [&](int d) { return xv[q + 4 + d]; };
            auto gxp = [&](int d) { return xp[q + 4 + d]; };
            auto gyu = [&](int d) {
                return d == -2 ? yu[0][q] : d == -1 ? yu[1][q] : d == 0 ? xu[4 + q]
                     : d == 1 ? yu[2][q] : yu[3][q];
            };
            auto gyv = [&](int d) {
                return d == -2 ? yv[0][q] : d == -1 ? yv[1][q] : d == 0 ? xv[4 + q]
                     : d == 1 ? yv[2][q] : yv[3][q];
            };
            auto gyp = [&](int d) {
                return d == -1 ? pm1[q] : d == 0 ? xp[4 + q] : pp1[q];
            };

            const float du_dx = g1f(gxu, ic, inv_sx, inv_2sx);
            const float du_dy = g1f(gyu, ir, inv_sy, inv_2sy);
            const float dv_dx = g1f(gxv, ic, inv_sx, inv_2sx);
            const float dv_dy = g1f(gyv, ir, inv_sy, inv_2sy);
            const float dp_dx = g1f(gxp, ic, inv_sx, inv_2sx);
            const float dp_dy = g1f(gyp, ir, inv_sy, inv_2sy);
            const float du_dxx = g2f(gxu, ic, inv_sx, inv_2sx);
            const float du_dyy = g2f(gyu, ir, inv_sy, inv_2sy);
            const float dv_dxx = g2f(gxv, ic, inv_sx, inv_2sx);
            const float dv_dyy = g2f(gyv, ir, inv_sy, inv_2sy);

            const float alpha = aa[q];
            const float dvg = du_dx + dv_dy;
            s_cont += dvg * dvg;
            // RHO = MU = 1
            const float xr_ = u * du_dx + v * du_dy + dp_dx - (du_dxx + du_dyy) + alpha * u;
            const float yr_ = u * dv_dx + v * dv_dy + dp_dy - (dv_dxx + dv_dyy) + alpha * v;
            s_ns += xr_ * xr_ + yr_ * yr_;
        }
    }

    // ---- block reduction: wave shuffle -> LDS -> one private slot write ----
    double a_base = s_base, a_bc = s_bc, a_cont = s_cont, a_ns = s_ns;
    #pragma unroll
    for (int off = 32; off > 0; off >>= 1) {
        a_base += __shfl_down(a_base, off);
        a_bc   += __shfl_down(a_bc, off);
        a_cont += __shfl_down(a_cont, off);
        a_ns   += __shfl_down(a_ns, off);
    }
    __shared__ double red[4][4];
    const int wave = tid >> 6, lane = tid & 63;
    if (lane == 0) {
        red[wave][0] = a_base; red[wave][1] = a_bc;
        red[wave][2] = a_cont; red[wave][3] = a_ns;
    }
    __syncthreads();
    if (tid == 0) {
        double b0 = 0, b1 = 0, b2 = 0, b3 = 0;
        #pragma unroll
        for (int w = 0; w < 4; ++w) {
            b0 += red[w][0]; b1 += red[w][1]; b2 += red[w][2]; b3 += red[w][3];
        }
        double* slot = ws + (size_t)blockIdx.x * 4;
        slot[0] = b0; slot[1] = b1; slot[2] = b2; slot[3] = b3;
    }
}

__global__ __launch_bounds__(256) void finalize_kernel(const double* __restrict__ ws,
                                                       float* __restrict__ out) {
    const int tid = threadIdx.x;
    double a0 = 0, a1 = 0, a2 = 0, a3 = 0;
    for (int b = tid; b < NBLK; b += 256) {
        const double* p = ws + (size_t)b * 4;
        a0 += p[0]; a1 += p[1]; a2 += p[2]; a3 += p[3];
    }
    #pragma unroll
    for (int off = 32; off > 0; off >>= 1) {
        a0 += __shfl_down(a0, off);
        a1 += __shfl_down(a1, off);
        a2 += __shfl_down(a2, off);
        a3 += __shfl_down(a3, off);
    }
    __shared__ double red[4][4];
    const int wave = tid >> 6, lane = tid & 63;
    if (lane == 0) {
        red[wave][0] = a0; red[wave][1] = a1; red[wave][2] = a2; red[wave][3] = a3;
    }
    __syncthreads();
    if (tid == 0) {
        double b0 = 0, b1 = 0, b2 = 0, b3 = 0;
        #pragma unroll
        for (int w = 0; w < 4; ++w) {
            b0 += red[w][0]; b1 += red[w][1]; b2 += red[w][2]; b3 += red[w][3];
        }
        const double loss_base = b0 / 300000.0;
        const double loss_cont = b2 / (256.0 * 126.0 * 126.0) / 1e-5;
        const double loss_ns   = b3 / (2.0 * 256.0 * 126.0 * 126.0) / 0.01;
        const double loss_bc   = b1 / (256.0 * 988.0);
        out[0] = (float)(0.10000000000000009 * loss_base +
                         0.3 * (loss_cont + loss_ns + loss_bc));
    }
}

extern "C" void kernel_launch(void* const* d_in, const int* in_sizes, int n_in,
                              void* d_out, int out_size, void* d_ws, size_t ws_size,
                              hipStream_t stream) {
    const float* inp = (const float*)d_in[0];
    const float* out = (const float*)d_in[1];
    const float* tgt = (const float*)d_in[2];
    float* o = (float*)d_out;
    double* ws = (double*)d_ws;

    hipLaunchKernelGGL(physics_loss_kernel, dim3(NBLK), dim3(256), 0, stream,
                       inp, out, tgt, ws);
    hipLaunchKernelGGL(finalize_kernel, dim3(1), dim3(256), 0, stream, ws, o);
}

// Round 4
// 33.415 us; speedup vs baseline: 24.0875x; 1.6471x over previous
//
#include <hip/hip_runtime.h>

// PhysicsLoss: fused base-MSE + boundary MSE + continuity + NS-residual losses.
// inputs  (256,1,128,128) f32, outputs (256,3,128,128) f32, targets (256,3,128,128) f32
// -> scalar f32.
//
// R3: kill scratch spills. R2's indexed arrays (xu[12], yu[4][4]) were demoted
// to scratch (VGPR=52, 98MB spill writes on dispatch 0). Rewrite with
// if-constexpr component selectors + template<int Q> per-pixel compute so every
// access is compile-time-constant -> pure VGPR.

#define HH 128
#define WW 128
#define NI 126   // interior size (1:H-1)
#define NBLK 4096

template <int I> __device__ __forceinline__ float gc(const float4& f) {
    if constexpr (I == 0) return f.x;
    else if constexpr (I == 1) return f.y;
    else if constexpr (I == 2) return f.z;
    else return f.w;
}

// x-neighborhood value at 12-wide index IDX (0..3 -> left f4, 4..7 -> mid, 8..11 -> right)
template <int IDX>
__device__ __forceinline__ float xsel(const float4& l, const float4& m, const float4& r) {
    if constexpr (IDX < 4) return gc<IDX>(l);
    else if constexpr (IDX < 8) return gc<IDX - 4>(m);
    else return gc<IDX - 8>(r);
}

// torch.gradient 1st derivative from named neighbor scalars
__device__ __forceinline__ float grad1s(float m1, float a0, float p1, int i,
                                        float inv_h, float inv_2h) {
    if (i == 0) return (p1 - a0) * inv_h;
    if (i == NI - 1) return (a0 - m1) * inv_h;
    return (p1 - m1) * inv_2h;
}

// torch.gradient 2nd derivative (grad of grad), from named neighbor scalars
__device__ __forceinline__ float grad2s(float m2, float m1, float a0, float p1, float p2,
                                        int i, float inv_h, float inv_2h) {
    if (i == 0) {
        const float d1 = (p2 - a0) * inv_2h, d0 = (p1 - a0) * inv_h;
        return (d1 - d0) * inv_h;
    }
    if (i == 1) {
        const float d1 = (p2 - a0) * inv_2h, dm1 = (a0 - m1) * inv_h;
        return (d1 - dm1) * inv_2h;
    }
    if (i == NI - 1) {
        const float d0 = (a0 - m1) * inv_h, dm1 = (a0 - m2) * inv_2h;
        return (d0 - dm1) * inv_h;
    }
    if (i == NI - 2) {
        const float d1 = (p1 - a0) * inv_h, dm1 = (a0 - m2) * inv_2h;
        return (d1 - dm1) * inv_2h;
    }
    return (p2 - 2.f * a0 + m2) * inv_2h * inv_2h;
}

struct Acc { float base, bc, cont, ns; };

template <int Q>
__device__ __forceinline__ void do_pixel(
    int r, int c0, bool midrow,
    const float4& uxl, const float4& uxm, const float4& uxr,
    const float4& uym2, const float4& uym1, const float4& uyp1, const float4& uyp2,
    const float4& vxl, const float4& vxm, const float4& vxr,
    const float4& vym2, const float4& vym1, const float4& vyp1, const float4& vyp2,
    const float4& pxl, const float4& pxm, const float4& pxr,
    const float4& pym1, const float4& pyp1,
    const float4& t0, const float4& t1, const float4& t2, const float4& av,
    Acc& acc) {
    const int c = c0 + Q;
    const float u0 = xsel<Q + 4>(uxl, uxm, uxr);
    const float v0 = xsel<Q + 4>(vxl, vxm, vxr);
    const float p0 = xsel<Q + 4>(pxl, pxm, pxr);

    {
        const float d0 = p0 - gc<Q>(t0);
        const float d1 = u0 - gc<Q>(t1);
        const float d2 = v0 - gc<Q>(t2);
        acc.base += d0 * d0 + d1 * d1 + d2 * d2;
    }
    // boundary pieces (corner multiplicity matches the reference concat)
    if (c == 0 && midrow) { const float d = u0 - 0.01f; acc.bc += d * d; }
    if (c == WW - 1 && midrow) { acc.bc += p0 * p0; }
    if (r == 0 || r == HH - 1) { acc.bc += u0 * u0 + v0 * v0; }
    if ((c == 0 || c == WW - 1) && !midrow) { acc.bc += u0 * u0 + v0 * v0; }

    if (r >= 1 && r <= HH - 2 && c >= 1 && c <= WW - 2) {
        const int ic = c - 1, ir = r - 1;
        const float inv_sx = 127.0f / 1.2f, inv_2sx = 127.0f / 2.4f;
        const float inv_sy = 127.0f / 0.8f, inv_2sy = 127.0f / 1.6f;

        // x-direction neighbors (compile-time component selects)
        const float uxm2 = xsel<Q + 2>(uxl, uxm, uxr), uxm1 = xsel<Q + 3>(uxl, uxm, uxr);
        const float uxp1 = xsel<Q + 5>(uxl, uxm, uxr), uxp2 = xsel<Q + 6>(uxl, uxm, uxr);
        const float vxm2 = xsel<Q + 2>(vxl, vxm, vxr), vxm1 = xsel<Q + 3>(vxl, vxm, vxr);
        const float vxp1 = xsel<Q + 5>(vxl, vxm, vxr), vxp2 = xsel<Q + 6>(vxl, vxm, vxr);
        const float pxm1 = xsel<Q + 3>(pxl, pxm, pxr), pxp1 = xsel<Q + 5>(pxl, pxm, pxr);
        // y-direction neighbors
        const float uym2s = gc<Q>(uym2), uym1s = gc<Q>(uym1);
        const float uyp1s = gc<Q>(uyp1), uyp2s = gc<Q>(uyp2);
        const float vym2s = gc<Q>(vym2), vym1s = gc<Q>(vym1);
        const float vyp1s = gc<Q>(vyp1), vyp2s = gc<Q>(vyp2);
        const float pym1s = gc<Q>(pym1), pyp1s = gc<Q>(pyp1);

        const float du_dx = grad1s(uxm1, u0, uxp1, ic, inv_sx, inv_2sx);
        const float du_dy = grad1s(uym1s, u0, uyp1s, ir, inv_sy, inv_2sy);
        const float dv_dx = grad1s(vxm1, v0, vxp1, ic, inv_sx, inv_2sx);
        const float dv_dy = grad1s(vym1s, v0, vyp1s, ir, inv_sy, inv_2sy);
        const float dp_dx = grad1s(pxm1, p0, pxp1, ic, inv_sx, inv_2sx);
        const float dp_dy = grad1s(pym1s, p0, pyp1s, ir, inv_sy, inv_2sy);
        const float du_dxx = grad2s(uxm2, uxm1, u0, uxp1, uxp2, ic, inv_sx, inv_2sx);
        const float du_dyy = grad2s(uym2s, uym1s, u0, uyp1s, uyp2s, ir, inv_sy, inv_2sy);
        const float dv_dxx = grad2s(vxm2, vxm1, v0, vxp1, vxp2, ic, inv_sx, inv_2sx);
        const float dv_dyy = grad2s(vym2s, vym1s, v0, vyp1s, vyp2s, ir, inv_sy, inv_2sy);

        const float alpha = gc<Q>(av);
        const float dvg = du_dx + dv_dy;
        acc.cont += dvg * dvg;
        // RHO = MU = 1
        const float xr_ = u0 * du_dx + v0 * du_dy + dp_dx - (du_dxx + du_dyy) + alpha * u0;
        const float yr_ = u0 * dv_dx + v0 * dv_dy + dp_dy - (dv_dxx + dv_dyy) + alpha * v0;
        acc.ns += xr_ * xr_ + yr_ * yr_;
    }
}

__global__ __launch_bounds__(256) void physics_loss_kernel(
    const float* __restrict__ inp, const float* __restrict__ out,
    const float* __restrict__ tgt, double* __restrict__ ws) {
    const int tid = threadIdx.x;
    const int grp = tid & 31;        // float4 group within row (32 per row)
    const int rloc = tid >> 5;       // 8 rows per block
    const int bid = blockIdx.x;
    const int b = bid >> 4;          // batch
    const int r = ((bid & 15) << 3) | rloc;
    const int c0 = grp << 2;

    const float* O = out + (size_t)b * 3 * HH * WW;
    const float* T = tgt + (size_t)b * 3 * HH * WW;
    const float* A = inp + (size_t)b * HH * WW;
    const float* P = O;
    const float* U = O + HH * WW;
    const float* V = O + 2 * HH * WW;

    const int gl = grp == 0 ? 0 : grp - 1;
    const int gr = grp == 31 ? 31 : grp + 1;
    const int rm2 = r < 2 ? 0 : r - 2;
    const int rm1 = r < 1 ? 0 : r - 1;
    const int rp1 = r > 126 ? 127 : r + 1;
    const int rp2 = r > 125 ? 127 : r + 2;

    auto ld = [&](const float* base, int row, int gg) {
        return reinterpret_cast<const float4*>(base + row * WW)[gg];
    };

    // 23 independent float4 loads, all kept in VGPRs
    const float4 uxl = ld(U, r, gl), uxm = ld(U, r, grp), uxr = ld(U, r, gr);
    const float4 uym2 = ld(U, rm2, grp), uym1 = ld(U, rm1, grp);
    const float4 uyp1 = ld(U, rp1, grp), uyp2 = ld(U, rp2, grp);
    const float4 vxl = ld(V, r, gl), vxm = ld(V, r, grp), vxr = ld(V, r, gr);
    const float4 vym2 = ld(V, rm2, grp), vym1 = ld(V, rm1, grp);
    const float4 vyp1 = ld(V, rp1, grp), vyp2 = ld(V, rp2, grp);
    const float4 pxl = ld(P, r, gl), pxm = ld(P, r, grp), pxr = ld(P, r, gr);
    const float4 pym1 = ld(P, rm1, grp), pyp1 = ld(P, rp1, grp);
    const float4 t0 = ld(T, r, grp);
    const float4 t1 = ld(T + HH * WW, r, grp);
    const float4 t2 = ld(T + 2 * HH * WW, r, grp);
    const float4 av = ld(A, r, grp);

    const bool midrow = (r >= 55 && r < 73);  // IN_BOT=55, IN_TOP=73
    Acc acc = {0.f, 0.f, 0.f, 0.f};

    do_pixel<0>(r, c0, midrow, uxl, uxm, uxr, uym2, uym1, uyp1, uyp2,
                vxl, vxm, vxr, vym2, vym1, vyp1, vyp2,
                pxl, pxm, pxr, pym1, pyp1, t0, t1, t2, av, acc);
    do_pixel<1>(r, c0, midrow, uxl, uxm, uxr, uym2, uym1, uyp1, uyp2,
                vxl, vxm, vxr, vym2, vym1, vyp1, vyp2,
                pxl, pxm, pxr, pym1, pyp1, t0, t1, t2, av, acc);
    do_pixel<2>(r, c0, midrow, uxl, uxm, uxr, uym2, uym1, uyp1, uyp2,
                vxl, vxm, vxr, vym2, vym1, vyp1, vyp2,
                pxl, pxm, pxr, pym1, pyp1, t0, t1, t2, av, acc);
    do_pixel<3>(r, c0, midrow, uxl, uxm, uxr, uym2, uym1, uyp1, uyp2,
                vxl, vxm, vxr, vym2, vym1, vyp1, vyp2,
                pxl, pxm, pxr, pym1, pyp1, t0, t1, t2, av, acc);

    // ---- block reduction: wave shuffle -> LDS -> one private slot write ----
    double a_base = acc.base, a_bc = acc.bc, a_cont = acc.cont, a_ns = acc.ns;
    #pragma unroll
    for (int off = 32; off > 0; off >>= 1) {
        a_base += __shfl_down(a_base, off);
        a_bc   += __shfl_down(a_bc, off);
        a_cont += __shfl_down(a_cont, off);
        a_ns   += __shfl_down(a_ns, off);
    }
    __shared__ double red[4][4];
    const int wave = tid >> 6, lane = tid & 63;
    if (lane == 0) {
        red[wave][0] = a_base; red[wave][1] = a_bc;
        red[wave][2] = a_cont; red[wave][3] = a_ns;
    }
    __syncthreads();
    if (tid == 0) {
        double b0 = 0, b1 = 0, b2 = 0, b3 = 0;
        #pragma unroll
        for (int w = 0; w < 4; ++w) {
            b0 += red[w][0]; b1 += red[w][1]; b2 += red[w][2]; b3 += red[w][3];
        }
        double* slot = ws + (size_t)blockIdx.x * 4;
        slot[0] = b0; slot[1] = b1; slot[2] = b2; slot[3] = b3;
    }
}

__global__ __launch_bounds__(256) void finalize_kernel(const double* __restrict__ ws,
                                                       float* __restrict__ out) {
    const int tid = threadIdx.x;
    double a0 = 0, a1 = 0, a2 = 0, a3 = 0;
    for (int b = tid; b < NBLK; b += 256) {
        const double* p = ws + (size_t)b * 4;
        a0 += p[0]; a1 += p[1]; a2 += p[2]; a3 += p[3];
    }
    #pragma unroll
    for (int off = 32; off > 0; off >>= 1) {
        a0 += __shfl_down(a0, off);
        a1 += __shfl_down(a1, off);
        a2 += __shfl_down(a2, off);
        a3 += __shfl_down(a3, off);
    }
    __shared__ double red[4][4];
    const int wave = tid >> 6, lane = tid & 63;
    if (lane == 0) {
        red[wave][0] = a0; red[wave][1] = a1; red[wave][2] = a2; red[wave][3] = a3;
    }
    __syncthreads();
    if (tid == 0) {
        double b0 = 0, b1 = 0, b2 = 0, b3 = 0;
        #pragma unroll
        for (int w = 0; w < 4; ++w) {
            b0 += red[w][0]; b1 += red[w][1]; b2 += red[w][2]; b3 += red[w][3];
        }
        const double loss_base = b0 / 300000.0;
        const double loss_cont = b2 / (256.0 * 126.0 * 126.0) / 1e-5;
        const double loss_ns   = b3 / (2.0 * 256.0 * 126.0 * 126.0) / 0.01;
        const double loss_bc   = b1 / (256.0 * 988.0);
        out[0] = (float)(0.10000000000000009 * loss_base +
                         0.3 * (loss_cont + loss_ns + loss_bc));
    }
}

extern "C" void kernel_launch(void* const* d_in, const int* in_sizes, int n_in,
                              void* d_out, int out_size, void* d_ws, size_t ws_size,
                              hipStream_t stream) {
    const float* inp = (const float*)d_in[0];
    const float* out = (const float*)d_in[1];
    const float* tgt = (const float*)d_in[2];
    float* o = (float*)d_out;
    double* ws = (double*)d_ws;

    hipLaunchKernelGGL(physics_loss_kernel, dim3(NBLK), dim3(256), 0, stream,
                       inp, out, tgt, ws);
    hipLaunchKernelGGL(finalize_kernel, dim3(1), dim3(256), 0, stream, ws, o);
}